// Round 3
// baseline (264.956 us; speedup 1.0000x reference)
//
#include <hip/hip_runtime.h>

// RotaryEmbedding2D: out[b,s] is a 64x64 block-diagonal rotation matrix.
// B=16, S=1024, D=64, q=16, h=32. BASE=10000, SCALE=1.
// For half-index h in [0,32): angle = (h<16 ? x : y) * 10000^{-(h%16)/16}
// Row 2h:   col 2h = cos, col 2h+1 = -sin
// Row 2h+1: col 2h = sin, col 2h+1 =  cos
// Output 256 MiB fp32 -> pure write-BW bound. Target: fill rate ~6.5 TB/s (~42 us).

#define NBS 16384        // B*S
#define MPB 8            // matrices per block
#define NBLK (NBS / MPB) // 2048 blocks

// Native clang vector: __builtin_nontemporal_store requires a real vector
// type, not HIP's struct-based float4.
typedef float vfloat4 __attribute__((ext_vector_type(4)));

__global__ __launch_bounds__(256) void rope2d_kernel(
    const float* __restrict__ spa,   // (B,S,2)
    float* __restrict__ out)         // (B,S,64,64)
{
    const int t   = threadIdx.x;          // 0..255
    const int bs0 = blockIdx.x * MPB;     // first matrix of this block

    __shared__ float ssin[MPB * 32];
    __shared__ float scos[MPB * 32];

    // Exactly one sincos per thread: matrix m = t>>5 (0..7), half-index h = t&31.
    {
        const int m = t >> 5;
        const int h = t & 31;
        const float xy   = spa[(bs0 + m) * 2 + (h >> 4)];  // h<16 -> x, else y
        const int   i    = h & 15;
        const float invf = exp2f(-(float)i * 0.83048202372184059f); // 10000^(-i/16)
        float s, c;
        sincosf(xy * invf, &s, &c);
        ssin[t] = s;
        scos[t] = c;
    }
    __syncthreads();

    // Block writes 8 matrices = 8192 float4 groups = 128 KiB, contiguous.
    // Thread t writes groups g = t + 256k, k=0..31 -> each wave-store is a
    // contiguous, aligned 1 KiB segment. Group g: matrix m=g>>10,
    // row=(g>>4)&63, colgroup=g&15 (= t&15, loop-invariant).
    vfloat4* outv = (vfloat4*)out + (size_t)bs0 * 1024;
    const int cg = t & 15;

    #pragma unroll
    for (int k = 0; k < 32; ++k) {
        const int g   = t + k * 256;
        const int row = (g >> 4) & 63;
        vfloat4 v = (vfloat4)(0.f, 0.f, 0.f, 0.f);
        if ((row >> 2) == cg) {           // the single nonzero group in this row
            const int m = g >> 10;
            const int h = row >> 1;
            const float s = ssin[m * 32 + h];
            const float c = scos[m * 32 + h];
            const float e0 = (row & 1) ? s : c;   // odd row: sin,cos ; even: cos,-sin
            const float e1 = (row & 1) ? c : -s;
            if (row & 2) { v.z = e0; v.w = e1; }  // pair at offset 2 in group
            else         { v.x = e0; v.y = e1; }  // pair at offset 0
        }
        __builtin_nontemporal_store(v, &outv[g]); // streaming store: no L2 allocate
    }
}

extern "C" void kernel_launch(void* const* d_in, const int* in_sizes, int n_in,
                              void* d_out, int out_size, void* d_ws, size_t ws_size,
                              hipStream_t stream) {
    const float* spa = (const float*)d_in[0];
    float* out = (float*)d_out;
    rope2d_kernel<<<NBLK, 256, 0, stream>>>(spa, out);
}

// Round 4
// 255.024 us; speedup vs baseline: 1.0389x; 1.0389x over previous
//
#include <hip/hip_runtime.h>

// RotaryEmbedding2D: out[b,s] is a 64x64 block-diagonal rotation matrix.
// B=16, S=1024, D=64, q=16, h=32. BASE=10000, SCALE=1.
// For half-index h in [0,32): angle = (h<16 ? x : y) * 10000^{-(h%16)/16}
// Row 2h:   col 2h = cos, col 2h+1 = -sin
// Row 2h+1: col 2h = sin, col 2h+1 =  cos
//
// Two-pass: (1) zero-fill 128 KiB/block exactly like fillBufferAligned
// (no per-iter VALU -> store-issue limited at ~6.3 TB/s), (2) overwrite the
// 512 nonzero 16B groups; they merge with the zero lines in L2, so HBM
// write traffic stays 256 MiB. Regular stores (NOT nontemporal) so L2
// write-combines. __syncthreads drains vmcnt -> pass1 < pass2 ordering.

#define NBS 16384        // B*S
#define MPB 8            // matrices per block
#define NBLK (NBS / MPB) // 2048 blocks

typedef float vfloat4 __attribute__((ext_vector_type(4)));

__global__ __launch_bounds__(256) void rope2d_kernel(
    const float* __restrict__ spa,   // (B,S,2)
    float* __restrict__ out)         // (B,S,64,64)
{
    const int t   = threadIdx.x;          // 0..255
    const int bs0 = blockIdx.x * MPB;     // first matrix of this block

    __shared__ float ssin[MPB * 32];
    __shared__ float scos[MPB * 32];

    // One sincos per thread: matrix m = t>>5, half-index h = t&31.
    {
        const int m = t >> 5;
        const int h = t & 31;
        const float xy   = spa[(bs0 + m) * 2 + (h >> 4)];  // h<16 -> x, else y
        const int   i    = h & 15;
        const float invf = exp2f(-(float)i * 0.83048202372184059f); // 10000^(-i/16)
        float s, c;
        sincosf(xy * invf, &s, &c);
        ssin[t] = s;
        scos[t] = c;
    }

    // ---- Pass 1: pure zero-fill of this block's 8 matrices (128 KiB). ----
    // Thread t stores float4 groups g = t + 256k: each wave store is a
    // contiguous aligned 1 KiB segment; no per-iteration logic at all.
    vfloat4* outv = (vfloat4*)out + (size_t)bs0 * 1024;
    const vfloat4 z = (vfloat4)(0.f, 0.f, 0.f, 0.f);
    #pragma unroll
    for (int k = 0; k < 32; ++k)
        outv[t + k * 256] = z;

    // Drains vmcnt + lgkmcnt: pass-1 stores reach L2 before pass 2 issues,
    // and LDS sin/cos is visible.
    __syncthreads();

    // ---- Pass 2: overwrite the 512 nonzero groups (8 mats x 64 rows). ----
    // Row `row` of matrix m has its only nonzero float4 group at colgroup
    // row>>2; within it the (e0,e1) pair sits at offset row&2.
    #pragma unroll
    for (int j = 0; j < 2; ++j) {
        const int idx = t + j * 256;     // 0..511
        const int m   = idx >> 6;        // matrix 0..7
        const int row = idx & 63;        // row 0..63
        const int h   = row >> 1;
        const float s = ssin[m * 32 + h];
        const float c = scos[m * 32 + h];
        const float e0 = (row & 1) ? s : c;   // odd row: sin,cos ; even: cos,-sin
        const float e1 = (row & 1) ? c : -s;
        vfloat4 v = z;
        if (row & 2) { v.z = e0; v.w = e1; }
        else         { v.x = e0; v.y = e1; }
        outv[m * 1024 + row * 16 + (row >> 2)] = v;
    }
}

extern "C" void kernel_launch(void* const* d_in, const int* in_sizes, int n_in,
                              void* d_out, int out_size, void* d_ws, size_t ws_size,
                              hipStream_t stream) {
    const float* spa = (const float*)d_in[0];
    float* out = (float*)d_out;
    rope2d_kernel<<<NBLK, 256, 0, stream>>>(spa, out);
}